// Round 2
// baseline (1835.919 us; speedup 1.0000x reference)
//
#include <hip/hip_runtime.h>
#include <hip/hip_bf16.h>

// PausePredictor: concat(enc, windowed textEmb) -> conv1(K=3,272->256) -> flexsig -> LN
//                 -> conv2(K=3,256->256) -> flexsig -> LN -> proj(256->1) -> mask
// Round 2: fused f32 baseline, vectorized staging + epilogue. VALU-bound (~107 GFLOP).

#define BB 64
#define TT 2048
#define HH 256
#define FSZ 256
#define KW 3
#define WIN 16
#define CIN1 (HH + WIN)   // 272
#define TILE_T 64

// ---------------- flex sigmoid ----------------
__device__ __forceinline__ float flexsig(float x, float a, float b, float c,
                                         float invc, float d) {
  float ax = fabsf(x);
  // (b*ax)^c ; x==0 -> log(0)=-inf -> exp(-inf)=0, correct
  float t = __expf(c * __logf(b * ax));
  float den = __expf(invc * __logf(1.0f + t));
  return a * b * x / den + d * x;
}

// ---------------- mask dtype detector ----------------
// flag: 0 = int32 words {0,1}, 1 = packed bytes (bool/int8), 2 = float32
__global__ void detect_mask_kernel(const unsigned int* __restrict__ m,
                                   int* __restrict__ flag) {
  __shared__ int s_big, s_flt;
  if (threadIdx.x == 0) { s_big = 0; s_flt = 0; }
  __syncthreads();
  int big = 0, flt = 0;
  const int nwords = (BB * TT) / 4;  // safe in-bounds for all 3 layouts
  for (int i = threadIdx.x; i < nwords; i += blockDim.x) {
    unsigned int w = m[i];
    if (w == 0x3F800000u) flt = 1;       // 1.0f bit pattern
    else if (w > 1u) big = 1;            // packed bool bytes
  }
  if (big) atomicOr(&s_big, 1);
  if (flt) atomicOr(&s_flt, 1);
  __syncthreads();
  if (threadIdx.x == 0) flag[0] = s_flt ? 2 : (s_big ? 1 : 0);
}

__device__ __forceinline__ bool read_mask(const void* maskp, size_t i, int fl) {
  if (fl == 0) return ((const int*)maskp)[i] != 0;
  if (fl == 1) return ((const unsigned char*)maskp)[i] != 0;
  return ((const float*)maskp)[i] != 0.0f;
}

// ---------------- weight repack: [f][c][k] -> [k][c][f] (lane-coalesced) ----------------
__global__ void repack_w(const float* __restrict__ w1, const float* __restrict__ w2,
                         float* __restrict__ w1t, float* __restrict__ w2t) {
  int idx = blockIdx.x * blockDim.x + threadIdx.x;
  const int n1 = FSZ * CIN1 * KW;
  if (idx < n1) {
    int f = idx % FSZ;
    int rest = idx / FSZ;
    int c = rest % CIN1;
    int k = rest / CIN1;
    w1t[idx] = w1[(f * CIN1 + c) * KW + k];
  }
  const int n2 = FSZ * FSZ * KW;
  if (idx < n2) {
    int f = idx % FSZ;
    int rest = idx / FSZ;
    int c = rest % FSZ;
    int k = rest / FSZ;
    w2t[idx] = w2[(f * FSZ + c) * KW + k];
  }
}

// ---------------- K1: conv1 + flexsig + LN -> y1 ----------------
__global__ __launch_bounds__(256, 2)
void k1_conv1(const float* __restrict__ enc, const float* __restrict__ temb,
              const float* __restrict__ w1t, const float* __restrict__ b1,
              const float* __restrict__ fa, const float* __restrict__ fb,
              const float* __restrict__ fc, const float* __restrict__ fd,
              const float* __restrict__ g1, const float* __restrict__ be1,
              float* __restrict__ y1, int b0) {
  __shared__ float xs[(TILE_T + 2) * CIN1];   // 66*272*4 = 71808 B
  __shared__ float mu_s[TILE_T];
  __shared__ float rs_s[TILE_T];

  const int tid = threadIdx.x;
  const int b = b0 + blockIdx.y;          // absolute batch for inputs
  const int by = blockIdx.y;              // chunk-relative for y1
  const int t0 = blockIdx.x * TILE_T;

  // ---- stage input tile (concat built on the fly), float4 ----
  for (int i = tid; i < (TILE_T + 2) * (HH / 4); i += 256) {
    int r = i >> 6;                 // HH/4 = 64 float4 per row
    int c4 = (i & 63) * 4;
    int tt = t0 + r - 1;
    float4 v = make_float4(0.f, 0.f, 0.f, 0.f);
    if (tt >= 0 && tt < TT)
      v = *reinterpret_cast<const float4*>(&enc[((size_t)b * TT + tt) * HH + c4]);
    *reinterpret_cast<float4*>(&xs[r * CIN1 + c4]) = v;
  }
  for (int i = tid; i < (TILE_T + 2) * WIN; i += 256) {
    int r = i >> 4;
    int w = i & 15;
    int tt = t0 + r - 1;
    float v = 0.0f;
    if (tt >= 0 && tt < TT) {
      int src = tt - w;
      v = (src >= 0) ? temb[(size_t)b * TT + src] : -1.0f;
    }
    xs[r * CIN1 + HH + w] = v;
  }
  __syncthreads();

  // ---- conv: thread owns channels f, f+128 over 32 timesteps ----
  const int f = tid & 127;
  const int th = tid >> 7;
  const int rbase = th * 32;

  float acc0[32], acc1[32];
#pragma unroll
  for (int i = 0; i < 32; ++i) { acc0[i] = 0.0f; acc1[i] = 0.0f; }

  for (int cg = 0; cg < CIN1 / 4; ++cg) {
    const int c4 = cg * 4;
    float wv0[3][4], wv1[3][4];
#pragma unroll
    for (int k = 0; k < 3; ++k)
#pragma unroll
      for (int j = 0; j < 4; ++j) {
        const float* wp = w1t + (size_t)((k * CIN1 + c4 + j) * FSZ) + f;
        wv0[k][j] = wp[0];
        wv1[k][j] = wp[128];
      }
#pragma unroll
    for (int tc = 0; tc < 4; ++tc) {
      float4 xr[10];
      const int r0 = rbase + tc * 8;
#pragma unroll
      for (int j = 0; j < 10; ++j)
        xr[j] = *reinterpret_cast<const float4*>(&xs[(r0 + j) * CIN1 + c4]);
#pragma unroll
      for (int jt = 0; jt < 8; ++jt) {
        const int tl = tc * 8 + jt;
#pragma unroll
        for (int k = 0; k < 3; ++k) {
          const float4 xv = xr[jt + k];
          acc0[tl] = fmaf(xv.x, wv0[k][0], acc0[tl]);
          acc0[tl] = fmaf(xv.y, wv0[k][1], acc0[tl]);
          acc0[tl] = fmaf(xv.z, wv0[k][2], acc0[tl]);
          acc0[tl] = fmaf(xv.w, wv0[k][3], acc0[tl]);
          acc1[tl] = fmaf(xv.x, wv1[k][0], acc1[tl]);
          acc1[tl] = fmaf(xv.y, wv1[k][1], acc1[tl]);
          acc1[tl] = fmaf(xv.z, wv1[k][2], acc1[tl]);
          acc1[tl] = fmaf(xv.w, wv1[k][3], acc1[tl]);
        }
      }
    }
  }

  __syncthreads();  // done reading xs; reuse as y-buffer
  float* yb = xs;   // 64*256 = 16384 floats <= 17952

  const float A = fa[0], Bf = fb[0], Cf = fc[0], Df = fd[0];
  const float invc = 1.0f / Cf;
  const float bia0 = b1[f], bia1 = b1[f + 128];
#pragma unroll
  for (int tl = 0; tl < 32; ++tl) {
    int t = rbase + tl;
    yb[t * FSZ + f]       = flexsig(acc0[tl] + bia0, A, Bf, Cf, invc, Df);
    yb[t * FSZ + f + 128] = flexsig(acc1[tl] + bia1, A, Bf, Cf, invc, Df);
  }
  __syncthreads();

  // ---- LN stats: 4 threads per timestep, bank-rotated reads ----
  {
    const int t = tid >> 2, g = tid & 3;
    float sum = 0.0f, ssq = 0.0f;
#pragma unroll
    for (int jj = 0; jj < 16; ++jj) {
      int col = g * 64 + ((jj + t) & 15) * 4;
      float4 v = *reinterpret_cast<const float4*>(&yb[t * FSZ + col]);
      sum += v.x + v.y + v.z + v.w;
      ssq += v.x * v.x + v.y * v.y + v.z * v.z + v.w * v.w;
    }
    sum += __shfl_xor(sum, 1); ssq += __shfl_xor(ssq, 1);
    sum += __shfl_xor(sum, 2); ssq += __shfl_xor(ssq, 2);
    float mu = sum * (1.0f / FSZ);
    float var = ssq * (1.0f / FSZ) - mu * mu;
    if (g == 0) { mu_s[t] = mu; rs_s[t] = rsqrtf(var + 1e-5f); }
  }
  __syncthreads();

  // ---- normalize + write (float4, coalesced) ----
  {
    const int c4 = (tid & 63) * 4;
    const float4 gg = *reinterpret_cast<const float4*>(&g1[c4]);
    const float4 bb2 = *reinterpret_cast<const float4*>(&be1[c4]);
    for (int t2 = (tid >> 6); t2 < TILE_T; t2 += 4) {
      const float mu = mu_s[t2], rs = rs_s[t2];
      float4 v = *reinterpret_cast<const float4*>(&yb[t2 * FSZ + c4]);
      v.x = (v.x - mu) * rs * gg.x + bb2.x;
      v.y = (v.y - mu) * rs * gg.y + bb2.y;
      v.z = (v.z - mu) * rs * gg.z + bb2.z;
      v.w = (v.w - mu) * rs * gg.w + bb2.w;
      *reinterpret_cast<float4*>(&y1[((size_t)by * TT + (t0 + t2)) * FSZ + c4]) = v;
    }
  }
}

// ---------------- K2: conv2 + flexsig + LN + proj + mask -> out ----------------
__global__ __launch_bounds__(256, 2)
void k2_conv2(const float* __restrict__ y1, const float* __restrict__ w2t,
              const float* __restrict__ b2,
              const float* __restrict__ fa, const float* __restrict__ fb,
              const float* __restrict__ fc, const float* __restrict__ fd,
              const float* __restrict__ g2, const float* __restrict__ be2,
              const float* __restrict__ wl, const float* __restrict__ bl,
              const void* __restrict__ maskp, const int* __restrict__ flag,
              float* __restrict__ out, int b0) {
  __shared__ float xs[(TILE_T + 2) * FSZ];   // 66*256*4 = 67584 B
  __shared__ float mu_s[TILE_T];
  __shared__ float rs_s[TILE_T];

  const int tid = threadIdx.x;
  const int b = b0 + blockIdx.y;
  const int by = blockIdx.y;
  const int t0 = blockIdx.x * TILE_T;

  // ---- stage input tile, float4 ----
  for (int i = tid; i < (TILE_T + 2) * (FSZ / 4); i += 256) {
    int r = i >> 6;
    int c4 = (i & 63) * 4;
    int tt = t0 + r - 1;
    float4 v = make_float4(0.f, 0.f, 0.f, 0.f);
    if (tt >= 0 && tt < TT)
      v = *reinterpret_cast<const float4*>(&y1[((size_t)by * TT + tt) * FSZ + c4]);
    *reinterpret_cast<float4*>(&xs[r * FSZ + c4]) = v;
  }
  __syncthreads();

  const int f = tid & 127;
  const int th = tid >> 7;
  const int rbase = th * 32;

  float acc0[32], acc1[32];
#pragma unroll
  for (int i = 0; i < 32; ++i) { acc0[i] = 0.0f; acc1[i] = 0.0f; }

  for (int cg = 0; cg < FSZ / 4; ++cg) {
    const int c4 = cg * 4;
    float wv0[3][4], wv1[3][4];
#pragma unroll
    for (int k = 0; k < 3; ++k)
#pragma unroll
      for (int j = 0; j < 4; ++j) {
        const float* wp = w2t + (size_t)((k * FSZ + c4 + j) * FSZ) + f;
        wv0[k][j] = wp[0];
        wv1[k][j] = wp[128];
      }
#pragma unroll
    for (int tc = 0; tc < 4; ++tc) {
      float4 xr[10];
      const int r0 = rbase + tc * 8;
#pragma unroll
      for (int j = 0; j < 10; ++j)
        xr[j] = *reinterpret_cast<const float4*>(&xs[(r0 + j) * FSZ + c4]);
#pragma unroll
      for (int jt = 0; jt < 8; ++jt) {
        const int tl = tc * 8 + jt;
#pragma unroll
        for (int k = 0; k < 3; ++k) {
          const float4 xv = xr[jt + k];
          acc0[tl] = fmaf(xv.x, wv0[k][0], acc0[tl]);
          acc0[tl] = fmaf(xv.y, wv0[k][1], acc0[tl]);
          acc0[tl] = fmaf(xv.z, wv0[k][2], acc0[tl]);
          acc0[tl] = fmaf(xv.w, wv0[k][3], acc0[tl]);
          acc1[tl] = fmaf(xv.x, wv1[k][0], acc1[tl]);
          acc1[tl] = fmaf(xv.y, wv1[k][1], acc1[tl]);
          acc1[tl] = fmaf(xv.z, wv1[k][2], acc1[tl]);
          acc1[tl] = fmaf(xv.w, wv1[k][3], acc1[tl]);
        }
      }
    }
  }

  __syncthreads();
  float* yb = xs;   // 64*256 = 16384 floats <= 16896

  const float A = fa[0], Bf = fb[0], Cf = fc[0], Df = fd[0];
  const float invc = 1.0f / Cf;
  const float bia0 = b2[f], bia1 = b2[f + 128];
#pragma unroll
  for (int tl = 0; tl < 32; ++tl) {
    int t = rbase + tl;
    yb[t * FSZ + f]       = flexsig(acc0[tl] + bia0, A, Bf, Cf, invc, Df);
    yb[t * FSZ + f + 128] = flexsig(acc1[tl] + bia1, A, Bf, Cf, invc, Df);
  }
  __syncthreads();

  {
    const int t = tid >> 2, g = tid & 3;
    float sum = 0.0f, ssq = 0.0f;
#pragma unroll
    for (int jj = 0; jj < 16; ++jj) {
      int col = g * 64 + ((jj + t) & 15) * 4;
      float4 v = *reinterpret_cast<const float4*>(&yb[t * FSZ + col]);
      sum += v.x + v.y + v.z + v.w;
      ssq += v.x * v.x + v.y * v.y + v.z * v.z + v.w * v.w;
    }
    sum += __shfl_xor(sum, 1); ssq += __shfl_xor(ssq, 1);
    sum += __shfl_xor(sum, 2); ssq += __shfl_xor(ssq, 2);
    float mu = sum * (1.0f / FSZ);
    float var = ssq * (1.0f / FSZ) - mu * mu;
    if (g == 0) { mu_s[t] = mu; rs_s[t] = rsqrtf(var + 1e-5f); }
  }
  __syncthreads();

  // ---- LN + projection + mask ----
  {
    const int t = tid >> 2, g = tid & 3;
    const float mu = mu_s[t], rs = rs_s[t];
    float p = 0.0f;
#pragma unroll
    for (int jj = 0; jj < 16; ++jj) {
      int col = g * 64 + ((jj + t) & 15) * 4;
      float4 v  = *reinterpret_cast<const float4*>(&yb[t * FSZ + col]);
      float4 gv = *reinterpret_cast<const float4*>(&g2[col]);
      float4 bv = *reinterpret_cast<const float4*>(&be2[col]);
      float4 wv = *reinterpret_cast<const float4*>(&wl[col]);
      p += ((v.x - mu) * rs * gv.x + bv.x) * wv.x;
      p += ((v.y - mu) * rs * gv.y + bv.y) * wv.y;
      p += ((v.z - mu) * rs * gv.z + bv.z) * wv.z;
      p += ((v.w - mu) * rs * gv.w + bv.w) * wv.w;
    }
    p += __shfl_xor(p, 1);
    p += __shfl_xor(p, 2);
    if (g == 0) {
      int ti = t0 + t;
      size_t mi = (size_t)b * TT + ti;
      int fl = flag[0];
      bool m = read_mask(maskp, mi, fl);
      out[mi] = m ? 0.0f : (p + bl[0]);
    }
  }
}

// ---------------- host launch ----------------
extern "C" void kernel_launch(void* const* d_in, const int* in_sizes, int n_in,
                              void* d_out, int out_size, void* d_ws, size_t ws_size,
                              hipStream_t stream) {
  const float* enc  = (const float*)d_in[0];
  const void*  maskp= d_in[1];
  const float* temb = (const float*)d_in[2];
  const float* w1   = (const float*)d_in[3];
  const float* b1   = (const float*)d_in[4];
  const float* fa1  = (const float*)d_in[5];
  const float* fb1  = (const float*)d_in[6];
  const float* fc1  = (const float*)d_in[7];
  const float* fd1  = (const float*)d_in[8];
  const float* g1   = (const float*)d_in[9];
  const float* be1  = (const float*)d_in[10];
  const float* w2   = (const float*)d_in[11];
  const float* b2   = (const float*)d_in[12];
  const float* fa2  = (const float*)d_in[13];
  const float* fb2  = (const float*)d_in[14];
  const float* fc2  = (const float*)d_in[15];
  const float* fd2  = (const float*)d_in[16];
  const float* g2   = (const float*)d_in[17];
  const float* be2  = (const float*)d_in[18];
  const float* wl   = (const float*)d_in[19];
  const float* bl   = (const float*)d_in[20];
  float* out = (float*)d_out;

  char* ws = (char*)d_ws;
  const size_t w1t_bytes = (size_t)KW * CIN1 * FSZ * 4;   // 835584
  const size_t w2t_bytes = (size_t)KW * FSZ * FSZ * 4;    // 786432
  float* w1t = (float*)ws;
  float* w2t = (float*)(ws + w1t_bytes);
  int*   flag = (int*)(ws + w1t_bytes + w2t_bytes);
  float* y1  = (float*)(ws + w1t_bytes + w2t_bytes + 256);

  const size_t head = w1t_bytes + w2t_bytes + 256;
  const size_t perB = (size_t)TT * FSZ * sizeof(float);   // 2 MiB per batch row
  size_t avail = (ws_size > head) ? (ws_size - head) : 0;
  size_t cb = avail / perB;
  int chunkB = (cb >= BB) ? BB : (int)cb;
  if (chunkB < 1) chunkB = 1;   // last-resort; expect ws to be generous

  detect_mask_kernel<<<1, 256, 0, stream>>>((const unsigned int*)maskp, flag);
  {
    int n = FSZ * CIN1 * KW;   // max of the two repack sizes
    repack_w<<<(n + 255) / 256, 256, 0, stream>>>(w1, w2, w1t, w2t);
  }

  for (int b0 = 0; b0 < BB; b0 += chunkB) {
    int nb = (BB - b0 < chunkB) ? (BB - b0) : chunkB;
    dim3 grid(TT / TILE_T, nb);
    k1_conv1<<<grid, 256, 0, stream>>>(enc, temb, w1t, b1, fa1, fb1, fc1, fd1,
                                       g1, be1, y1, b0);
    k2_conv2<<<grid, 256, 0, stream>>>(y1, w2t, b2, fa2, fb2, fc2, fd2,
                                       g2, be2, wl, bl, maskp, flag, out, b0);
  }
}

// Round 4
// 484.195 us; speedup vs baseline: 3.7917x; 3.7917x over previous
//
#include <hip/hip_runtime.h>
#include <hip/hip_bf16.h>

// PausePredictor: concat(enc, windowed textEmb) -> conv1(K=3,272->256) -> flexsig -> LN
//                 -> conv2(K=3,256->256) -> flexsig -> LN -> proj(256->1) -> mask
// Round 4 (= Round 3 resubmit after acquisition timeout):
// bf16 MFMA convs (3 shifted GEMMs), fused flexsig/LN/proj epilogues.

#define BB 64
#define TT 2048
#define HH 256
#define FSZ 256
#define KW 3
#define WIN 16
#define CIN1 272
#define TILE_T 64

#define NCS1 9            // K-steps per shift, conv1 (288 padded / 32)
#define NK1 27            // 3 shifts * 9
#define CP1B 640          // LDS row stride bytes k1 (multiple of 128 for swizzle)
#define NCS2 8
#define NK2 24
#define CP2B 512

typedef __attribute__((ext_vector_type(8))) short bf16x8;
typedef __attribute__((ext_vector_type(4))) float f32x4;

__device__ __forceinline__ unsigned short f2bf(float f) {
  unsigned int u = __float_as_uint(f);
  unsigned int r = (u + 0x7fffu + ((u >> 16) & 1u)) >> 16;   // RNE
  return (unsigned short)r;
}

__device__ __forceinline__ float flexsig(float x, float a, float b, float c,
                                         float invc, float d) {
  float ax = fabsf(x);
  float t = __expf(c * __logf(b * ax));          // (b|x|)^c ; x=0 -> 0
  float den = __expf(invc * __logf(1.0f + t));   // (1+t)^(1/c)
  return a * b * x / den + d * x;
}

// ---------------- mask dtype detector ----------------
__global__ void detect_mask_kernel(const unsigned int* __restrict__ m,
                                   int* __restrict__ flag) {
  __shared__ int s_big, s_flt;
  if (threadIdx.x == 0) { s_big = 0; s_flt = 0; }
  __syncthreads();
  int big = 0, flt = 0;
  const int nwords = (BB * TT) / 4;
  for (int i = threadIdx.x; i < nwords; i += blockDim.x) {
    unsigned int w = m[i];
    if (w == 0x3F800000u) flt = 1;
    else if (w > 1u) big = 1;
  }
  if (big) atomicOr(&s_big, 1);
  if (flt) atomicOr(&s_flt, 1);
  __syncthreads();
  if (threadIdx.x == 0) flag[0] = s_flt ? 2 : (s_big ? 1 : 0);
}

__device__ __forceinline__ bool read_mask(const void* maskp, size_t i, int fl) {
  if (fl == 0) return ((const int*)maskp)[i] != 0;
  if (fl == 1) return ((const unsigned char*)maskp)[i] != 0;
  return ((const float*)maskp)[i] != 0.0f;
}

// ---------------- weight repack into per-lane MFMA B-fragment order ----------------
// wb[idx], idx = (((s*NCS + cs)*16 + nf)*64 + lane)*8 + j
// holds W[c = cs*32 + (lane>>4)*8 + j][f = nf*16 + (lane&15)] for shift s (bf16)
__global__ void repack_mfma(const float* __restrict__ w1, const float* __restrict__ w2,
                            unsigned short* __restrict__ wb1,
                            unsigned short* __restrict__ wb2) {
  int idx = blockIdx.x * blockDim.x + threadIdx.x;
  const int n1 = NK1 * 16 * 64 * 8;   // 221184
  if (idx < n1) {
    int j = idx & 7, lane = (idx >> 3) & 63, nf = (idx >> 9) & 15, rest = idx >> 13;
    int s = rest / NCS1, cs = rest - s * NCS1;
    int c = cs * 32 + (lane >> 4) * 8 + j;
    int f = nf * 16 + (lane & 15);
    float v = (c < CIN1) ? w1[(f * CIN1 + c) * KW + s] : 0.0f;
    wb1[idx] = f2bf(v);
  }
  const int n2 = NK2 * 16 * 64 * 8;   // 196608
  if (idx < n2) {
    int j = idx & 7, lane = (idx >> 3) & 63, nf = (idx >> 9) & 15, rest = idx >> 13;
    int s = rest >> 3, cs = rest & 7;
    int c = cs * 32 + (lane >> 4) * 8 + j;
    int f = nf * 16 + (lane & 15);
    wb2[idx] = f2bf(w2[(f * FSZ + c) * KW + s]);
  }
}

// ---------------- K1: conv1 + flexsig + LN -> y1 (bf16) ----------------
__global__ __launch_bounds__(256, 2)
void k1_mfma(const float* __restrict__ enc, const float* __restrict__ temb,
             const bf16x8* __restrict__ wb1, const float* __restrict__ b1g,
             const float* __restrict__ fa, const float* __restrict__ fb,
             const float* __restrict__ fc, const float* __restrict__ fd,
             const float* __restrict__ g1, const float* __restrict__ be1,
             unsigned short* __restrict__ y1, int b0) {
  __shared__ __attribute__((aligned(16))) char sA[66 * CP1B];   // 42240 B
  __shared__ float2 lnbuf[64][4];
  __shared__ float mu_s[64], rs_s[64];
  __shared__ float gs[256], bs[256], bias_s[256];

  const int tid = threadIdx.x;
  const int b = b0 + blockIdx.y;
  const int by = blockIdx.y;
  const int t0 = blockIdx.x * TILE_T;
  const int lane = tid & 63;
  const int wid = tid >> 6;
  const int l15 = lane & 15;
  const int lhi = lane >> 4;

  gs[tid] = g1[tid]; bs[tid] = be1[tid]; bias_s[tid] = b1g[tid];

  // ---- stage A tile (66 rows x 288 cols, bf16, swizzled) ----
  for (int i = tid; i < 66 * 36; i += 256) {
    int row = i / 36;
    int g = i - row * 36;
    int t = t0 + row - 1;
    bool tv = (t >= 0) && (t < TT);
    float x[8];
    if (g < 32) {
      if (tv) {
        const float4* p = reinterpret_cast<const float4*>(&enc[((size_t)b * TT + t) * HH + g * 8]);
        float4 v0 = p[0], v1 = p[1];
        x[0] = v0.x; x[1] = v0.y; x[2] = v0.z; x[3] = v0.w;
        x[4] = v1.x; x[5] = v1.y; x[6] = v1.z; x[7] = v1.w;
      } else {
#pragma unroll
        for (int j = 0; j < 8; ++j) x[j] = 0.0f;
      }
    } else if (g < 34) {
      int w0 = (g - 32) * 8;
#pragma unroll
      for (int j = 0; j < 8; ++j) {
        int w = w0 + j;
        float v = 0.0f;
        if (tv) v = (t - w >= 0) ? temb[(size_t)b * TT + t - w] : -1.0f;
        x[j] = v;
      }
    } else {
#pragma unroll
      for (int j = 0; j < 8; ++j) x[j] = 0.0f;
    }
    bf16x8 pk;
#pragma unroll
    for (int j = 0; j < 8; ++j) pk[j] = (short)f2bf(x[j]);
    int byte = row * CP1B + ((g * 16) ^ ((row & 7) << 4));
    *reinterpret_cast<bf16x8*>(&sA[byte]) = pk;
  }
  __syncthreads();

  // ---- MFMA k-loop: wave = M64 x N64 (cols wid*64..wid*64+63) ----
  f32x4 acc[4][4];
#pragma unroll
  for (int mf = 0; mf < 4; ++mf)
#pragma unroll
    for (int nf = 0; nf < 4; ++nf) acc[mf][nf] = (f32x4)(0.0f);

  auto loadA = [&](int ks, bf16x8 aF[4]) {
    int s = (ks >= 2 * NCS1) ? 2 : ((ks >= NCS1) ? 1 : 0);
    int cs = ks - s * NCS1;
    int row0 = l15 + s;
    int cb = (cs * 64 + lhi * 16) ^ ((row0 & 7) << 4);
    int base = row0 * CP1B + cb;
#pragma unroll
    for (int mf = 0; mf < 4; ++mf)
      aF[mf] = *reinterpret_cast<const bf16x8*>(&sA[base + mf * (16 * CP1B)]);
  };
  auto loadB = [&](int ks, bf16x8 bF[4]) {
    const bf16x8* p = wb1 + (size_t)(ks * 16 + wid * 4) * 64 + lane;
#pragma unroll
    for (int nf = 0; nf < 4; ++nf) bF[nf] = p[nf * 64];
  };
  auto mm = [&](bf16x8 aF[4], bf16x8 bF[4]) {
#pragma unroll
    for (int mf = 0; mf < 4; ++mf)
#pragma unroll
      for (int nf = 0; nf < 4; ++nf)
        acc[mf][nf] = __builtin_amdgcn_mfma_f32_16x16x32_bf16(aF[mf], bF[nf], acc[mf][nf], 0, 0, 0);
  };

  bf16x8 aP[4], bP[4], aQ[4], bQ[4];
  loadA(0, aP); loadB(0, bP);
  int ks = 0;
  for (; ks + 1 < NK1; ks += 2) {
    loadA(ks + 1, aQ); loadB(ks + 1, bQ);
    mm(aP, bP);
    if (ks + 2 < NK1) { loadA(ks + 2, aP); loadB(ks + 2, bP); }
    mm(aQ, bQ);
  }
  if (ks < NK1) mm(aP, bP);

  // ---- flexsig (in-register) ----
  const float fA = fa[0], fB = fb[0], fC = fc[0], fD = fd[0];
  const float inv_c = 1.0f / fC;
#pragma unroll
  for (int mf = 0; mf < 4; ++mf)
#pragma unroll
    for (int nf = 0; nf < 4; ++nf) {
      int col = wid * 64 + nf * 16 + l15;
      float bias = bias_s[col];
#pragma unroll
      for (int r = 0; r < 4; ++r)
        acc[mf][nf][r] = flexsig(acc[mf][nf][r] + bias, fA, fB, fC, inv_c, fD);
    }

  // ---- LN stats: per-row partials over this wave's 64 cols ----
#pragma unroll
  for (int mf = 0; mf < 4; ++mf)
#pragma unroll
    for (int r = 0; r < 4; ++r) {
      float s = 0.0f, q = 0.0f;
#pragma unroll
      for (int nf = 0; nf < 4; ++nf) {
        float v = acc[mf][nf][r];
        s += v; q += v * v;
      }
      s += __shfl_xor(s, 1); q += __shfl_xor(q, 1);
      s += __shfl_xor(s, 2); q += __shfl_xor(q, 2);
      s += __shfl_xor(s, 4); q += __shfl_xor(q, 4);
      s += __shfl_xor(s, 8); q += __shfl_xor(q, 8);
      if (l15 == 0) lnbuf[mf * 16 + lhi * 4 + r][wid] = make_float2(s, q);
    }
  __syncthreads();   // also: all waves done reading sA
  if (tid < 64) {
    float S = 0.0f, Q = 0.0f;
#pragma unroll
    for (int w = 0; w < 4; ++w) { S += lnbuf[tid][w].x; Q += lnbuf[tid][w].y; }
    float mu = S * (1.0f / 256.0f);
    float var = Q * (1.0f / 256.0f) - mu * mu;
    mu_s[tid] = mu; rs_s[tid] = rsqrtf(var + 1e-5f);
  }
  __syncthreads();

  // ---- normalize -> bf16 y-tile in LDS (reuse sA), swizzled rows ----
#pragma unroll
  for (int mf = 0; mf < 4; ++mf)
#pragma unroll
    for (int nf = 0; nf < 4; ++nf) {
      int col = wid * 64 + nf * 16 + l15;
      float gg = gs[col], bb = bs[col];
#pragma unroll
      for (int r = 0; r < 4; ++r) {
        int row = mf * 16 + lhi * 4 + r;
        float v = (acc[mf][nf][r] - mu_s[row]) * rs_s[row] * gg + bb;
        int byte = row * 512 + ((col * 2) ^ ((row & 7) << 4));
        *reinterpret_cast<unsigned short*>(&sA[byte]) = f2bf(v);
      }
    }
  __syncthreads();

  // ---- coalesced bf16 store of y1 ----
  for (int i = tid; i < 64 * 32; i += 256) {
    int row = i >> 5, g = i & 31;
    int byte = row * 512 + ((g * 16) ^ ((row & 7) << 4));
    bf16x8 v = *reinterpret_cast<const bf16x8*>(&sA[byte]);
    *reinterpret_cast<bf16x8*>(&y1[((size_t)by * TT + t0 + row) * FSZ + g * 8]) = v;
  }
}

// ---------------- K2: conv2 + flexsig + LN + proj + mask -> out ----------------
__global__ __launch_bounds__(256, 2)
void k2_mfma(const unsigned short* __restrict__ y1, const bf16x8* __restrict__ wb2,
             const float* __restrict__ b2g,
             const float* __restrict__ fa, const float* __restrict__ fb,
             const float* __restrict__ fc, const float* __restrict__ fd,
             const float* __restrict__ g2, const float* __restrict__ be2,
             const float* __restrict__ wl, const float* __restrict__ bl,
             const void* __restrict__ maskp, const int* __restrict__ flag,
             float* __restrict__ out, int b0) {
  __shared__ __attribute__((aligned(16))) char sA[66 * CP2B];   // 33792 B
  __shared__ float2 lnbuf[64][4];
  __shared__ float pbuf[64][4];
  __shared__ float mu_s[64], rs_s[64];
  __shared__ float gs[256], bs[256], bias_s[256], wls[256];

  const int tid = threadIdx.x;
  const int b = b0 + blockIdx.y;
  const int by = blockIdx.y;
  const int t0 = blockIdx.x * TILE_T;
  const int lane = tid & 63;
  const int wid = tid >> 6;
  const int l15 = lane & 15;
  const int lhi = lane >> 4;

  gs[tid] = g2[tid]; bs[tid] = be2[tid]; bias_s[tid] = b2g[tid]; wls[tid] = wl[tid];

  // ---- stage A tile (66 x 256 bf16, swizzled) ----
  for (int i = tid; i < 66 * 32; i += 256) {
    int row = i >> 5, g = i & 31;
    int t = t0 + row - 1;
    bf16x8 v;
#pragma unroll
    for (int j = 0; j < 8; ++j) v[j] = 0;
    if (t >= 0 && t < TT)
      v = *reinterpret_cast<const bf16x8*>(&y1[((size_t)by * TT + t) * FSZ + g * 8]);
    int byte = row * CP2B + ((g * 16) ^ ((row & 7) << 4));
    *reinterpret_cast<bf16x8*>(&sA[byte]) = v;
  }
  __syncthreads();

  f32x4 acc[4][4];
#pragma unroll
  for (int mf = 0; mf < 4; ++mf)
#pragma unroll
    for (int nf = 0; nf < 4; ++nf) acc[mf][nf] = (f32x4)(0.0f);

  auto loadA = [&](int ks, bf16x8 aF[4]) {
    int s = (ks >= 2 * NCS2) ? 2 : ((ks >= NCS2) ? 1 : 0);
    int cs = ks - s * NCS2;
    int row0 = l15 + s;
    int cb = (cs * 64 + lhi * 16) ^ ((row0 & 7) << 4);
    int base = row0 * CP2B + cb;
#pragma unroll
    for (int mf = 0; mf < 4; ++mf)
      aF[mf] = *reinterpret_cast<const bf16x8*>(&sA[base + mf * (16 * CP2B)]);
  };
  auto loadB = [&](int ks, bf16x8 bF[4]) {
    const bf16x8* p = wb2 + (size_t)(ks * 16 + wid * 4) * 64 + lane;
#pragma unroll
    for (int nf = 0; nf < 4; ++nf) bF[nf] = p[nf * 64];
  };
  auto mm = [&](bf16x8 aF[4], bf16x8 bF[4]) {
#pragma unroll
    for (int mf = 0; mf < 4; ++mf)
#pragma unroll
      for (int nf = 0; nf < 4; ++nf)
        acc[mf][nf] = __builtin_amdgcn_mfma_f32_16x16x32_bf16(aF[mf], bF[nf], acc[mf][nf], 0, 0, 0);
  };

  bf16x8 aP[4], bP[4], aQ[4], bQ[4];
  loadA(0, aP); loadB(0, bP);
  int ks = 0;
  for (; ks + 1 < NK2; ks += 2) {
    loadA(ks + 1, aQ); loadB(ks + 1, bQ);
    mm(aP, bP);
    if (ks + 2 < NK2) { loadA(ks + 2, aP); loadB(ks + 2, bP); }
    mm(aQ, bQ);
  }
  if (ks < NK2) mm(aP, bP);

  const float fA = fa[0], fB = fb[0], fC = fc[0], fD = fd[0];
  const float inv_c = 1.0f / fC;
#pragma unroll
  for (int mf = 0; mf < 4; ++mf)
#pragma unroll
    for (int nf = 0; nf < 4; ++nf) {
      int col = wid * 64 + nf * 16 + l15;
      float bias = bias_s[col];
#pragma unroll
      for (int r = 0; r < 4; ++r)
        acc[mf][nf][r] = flexsig(acc[mf][nf][r] + bias, fA, fB, fC, inv_c, fD);
    }

#pragma unroll
  for (int mf = 0; mf < 4; ++mf)
#pragma unroll
    for (int r = 0; r < 4; ++r) {
      float s = 0.0f, q = 0.0f;
#pragma unroll
      for (int nf = 0; nf < 4; ++nf) {
        float v = acc[mf][nf][r];
        s += v; q += v * v;
      }
      s += __shfl_xor(s, 1); q += __shfl_xor(q, 1);
      s += __shfl_xor(s, 2); q += __shfl_xor(q, 2);
      s += __shfl_xor(s, 4); q += __shfl_xor(q, 4);
      s += __shfl_xor(s, 8); q += __shfl_xor(q, 8);
      if (l15 == 0) lnbuf[mf * 16 + lhi * 4 + r][wid] = make_float2(s, q);
    }
  __syncthreads();
  if (tid < 64) {
    float S = 0.0f, Q = 0.0f;
#pragma unroll
    for (int w = 0; w < 4; ++w) { S += lnbuf[tid][w].x; Q += lnbuf[tid][w].y; }
    float mu = S * (1.0f / 256.0f);
    float var = Q * (1.0f / 256.0f) - mu * mu;
    mu_s[tid] = mu; rs_s[tid] = rsqrtf(var + 1e-5f);
  }
  __syncthreads();

  // ---- normalize + projection (in-register), reduce across lanes+waves ----
  float p[4][4];
#pragma unroll
  for (int mf = 0; mf < 4; ++mf)
#pragma unroll
    for (int r = 0; r < 4; ++r) p[mf][r] = 0.0f;
#pragma unroll
  for (int mf = 0; mf < 4; ++mf)
#pragma unroll
    for (int nf = 0; nf < 4; ++nf) {
      int col = wid * 64 + nf * 16 + l15;
      float gg = gs[col], bb = bs[col], ww = wls[col];
#pragma unroll
      for (int r = 0; r < 4; ++r) {
        int row = mf * 16 + lhi * 4 + r;
        float v = (acc[mf][nf][r] - mu_s[row]) * rs_s[row] * gg + bb;
        p[mf][r] += v * ww;
      }
    }
#pragma unroll
  for (int mf = 0; mf < 4; ++mf)
#pragma unroll
    for (int r = 0; r < 4; ++r) {
      float v = p[mf][r];
      v += __shfl_xor(v, 1);
      v += __shfl_xor(v, 2);
      v += __shfl_xor(v, 4);
      v += __shfl_xor(v, 8);
      if (l15 == 0) pbuf[mf * 16 + lhi * 4 + r][wid] = v;
    }
  __syncthreads();
  if (tid < 64) {
    float s = pbuf[tid][0] + pbuf[tid][1] + pbuf[tid][2] + pbuf[tid][3] + bl[0];
    int t = t0 + tid;
    size_t mi = (size_t)b * TT + t;
    bool m = read_mask(maskp, mi, flag[0]);
    out[mi] = m ? 0.0f : s;
  }
}

// ---------------- host launch ----------------
extern "C" void kernel_launch(void* const* d_in, const int* in_sizes, int n_in,
                              void* d_out, int out_size, void* d_ws, size_t ws_size,
                              hipStream_t stream) {
  const float* enc  = (const float*)d_in[0];
  const void*  maskp= d_in[1];
  const float* temb = (const float*)d_in[2];
  const float* w1   = (const float*)d_in[3];
  const float* b1   = (const float*)d_in[4];
  const float* fa1  = (const float*)d_in[5];
  const float* fb1  = (const float*)d_in[6];
  const float* fc1  = (const float*)d_in[7];
  const float* fd1  = (const float*)d_in[8];
  const float* g1   = (const float*)d_in[9];
  const float* be1  = (const float*)d_in[10];
  const float* w2   = (const float*)d_in[11];
  const float* b2   = (const float*)d_in[12];
  const float* fa2  = (const float*)d_in[13];
  const float* fb2  = (const float*)d_in[14];
  const float* fc2  = (const float*)d_in[15];
  const float* fd2  = (const float*)d_in[16];
  const float* g2   = (const float*)d_in[17];
  const float* be2  = (const float*)d_in[18];
  const float* wl   = (const float*)d_in[19];
  const float* bl   = (const float*)d_in[20];
  float* out = (float*)d_out;

  char* ws = (char*)d_ws;
  const size_t wb1_bytes = (size_t)NK1 * 16 * 64 * 8 * 2;  // 442368
  const size_t wb2_bytes = (size_t)NK2 * 16 * 64 * 8 * 2;  // 393216
  unsigned short* wb1 = (unsigned short*)ws;
  unsigned short* wb2 = (unsigned short*)(ws + wb1_bytes);
  int* flag = (int*)(ws + wb1_bytes + wb2_bytes);
  unsigned short* y1 = (unsigned short*)(ws + wb1_bytes + wb2_bytes + 256);

  const size_t head = wb1_bytes + wb2_bytes + 256;
  const size_t perB = (size_t)TT * FSZ * 2;                // 1 MiB per batch row (bf16)
  size_t avail = (ws_size > head) ? (ws_size - head) : 0;
  size_t cb = avail / perB;
  int chunkB = (cb >= BB) ? BB : (int)cb;
  if (chunkB < 1) chunkB = 1;

  detect_mask_kernel<<<1, 256, 0, stream>>>((const unsigned int*)maskp, flag);
  {
    int n = NK1 * 16 * 64 * 8;   // 221184 >= both repack sizes
    repack_mfma<<<(n + 255) / 256, 256, 0, stream>>>(w1, w2, wb1, wb2);
  }

  for (int b0 = 0; b0 < BB; b0 += chunkB) {
    int nb = (BB - b0 < chunkB) ? (BB - b0) : chunkB;
    dim3 grid(TT / TILE_T, nb);
    k1_mfma<<<grid, 256, 0, stream>>>(enc, temb, (const bf16x8*)wb1, b1,
                                      fa1, fb1, fc1, fd1, g1, be1, y1, b0);
    k2_mfma<<<grid, 256, 0, stream>>>(y1, (const bf16x8*)wb2, b2,
                                      fa2, fb2, fc2, fd2, g2, be2, wl, bl,
                                      maskp, flag, out, b0);
  }
}

// Round 8
// 415.142 us; speedup vs baseline: 4.4224x; 1.1663x over previous
//
#include <hip/hip_runtime.h>
#include <hip/hip_bf16.h>

// PausePredictor: concat(enc, windowed textEmb) -> conv1(K=3,272->256) -> flexsig -> LN
//                 -> conv2(K=3,256->256) -> flexsig -> LN -> proj(256->1) -> mask
// Round 8 (= Round 6/7 resubmit; broker timeouts, kernel has never run):
//   TILE_T=32, fully-unrolled pipelined K-loop, parallel mask-detect in prep.
//   CP1B=640: XOR swizzle (row&7)<<4 permutes within 128B blocks, so the
//   LDS row stride MUST be a multiple of 128 (576 caused cross-row collisions).

#define BB 64
#define TT 2048
#define HH 256
#define FSZ 256
#define KW 3
#define WIN 16
#define CIN1 272
#define TILE_T 32
#define ROWS (TILE_T + 2)      // 34

#define NCS1 9                 // K-steps per shift, conv1 (288 padded / 32)
#define NK1 27
#define CP1B 640               // k1 LDS row stride bytes (multiple of 128!)
#define NCS2 8
#define NK2 24
#define CP2B 512               // k2 LDS row stride bytes (multiple of 128)

typedef __attribute__((ext_vector_type(8))) short bf16x8;
typedef __attribute__((ext_vector_type(4))) float f32x4;

__device__ __forceinline__ unsigned short f2bf(float f) {
  unsigned int u = __float_as_uint(f);
  unsigned int r = (u + 0x7fffu + ((u >> 16) & 1u)) >> 16;   // RNE
  return (unsigned short)r;
}

__device__ __forceinline__ float flexsig(float x, float a, float b, float c,
                                         float invc, float d) {
  float ax = fabsf(x);
  float t = __expf(c * __logf(b * ax));          // (b|x|)^c ; x=0 -> 0
  float den = __expf(invc * __logf(1.0f + t));   // (1+t)^(1/c)
  return a * b * x / den + d * x;
}

__device__ __forceinline__ bool read_mask(const void* maskp, size_t i, int fl) {
  if (fl == 0) return ((const int*)maskp)[i] != 0;
  if (fl == 1) return ((const unsigned char*)maskp)[i] != 0;
  return ((const float*)maskp)[i] != 0.0f;
}

// ---------------- prep: weight repack (blocks 0..863) + mask detect (864..927) ----
// wb[idx], idx = (((s*NCS + cs)*16 + nf)*64 + lane)*8 + j
// holds W[c = cs*32 + (lane>>4)*8 + j][f = nf*16 + (lane&15)] for shift s (bf16)
__global__ void prep_kernel(const float* __restrict__ w1, const float* __restrict__ w2,
                            unsigned short* __restrict__ wb1,
                            unsigned short* __restrict__ wb2,
                            const unsigned int* __restrict__ m,
                            int* __restrict__ flag) {
  const int bid = blockIdx.x;
  if (bid < 864) {
    int idx = bid * 256 + threadIdx.x;           // < 221184 == n1 exactly
    {
      int j = idx & 7, lane = (idx >> 3) & 63, nf = (idx >> 9) & 15, rest = idx >> 13;
      int s = rest / NCS1, cs = rest - s * NCS1;
      int c = cs * 32 + (lane >> 4) * 8 + j;
      int f = nf * 16 + (lane & 15);
      float v = (c < CIN1) ? w1[(f * CIN1 + c) * KW + s] : 0.0f;
      wb1[idx] = f2bf(v);
    }
    const int n2 = NK2 * 16 * 64 * 8;            // 196608
    if (idx < n2) {
      int j = idx & 7, lane = (idx >> 3) & 63, nf = (idx >> 9) & 15, rest = idx >> 13;
      int s = rest >> 3, cs = rest & 7;
      int c = cs * 32 + (lane >> 4) * 8 + j;
      int f = nf * 16 + (lane & 15);
      wb2[idx] = f2bf(w2[(f * FSZ + c) * KW + s]);
    }
  } else {
    // mask dtype detect: flag[1]=saw word>1 (packed bytes), flag[2]=saw 1.0f (float)
    int t = (bid - 864) * 256 + threadIdx.x;     // 0..16383
    int big = 0, flt = 0;
    const int nwords = (BB * TT) / 4;            // safe in-bounds for all layouts
    for (int i = t; i < nwords; i += 64 * 256) {
      unsigned int w = m[i];
      if (w == 0x3F800000u) flt = 1;
      else if (w > 1u) big = 1;
    }
    if (__any(big) && (threadIdx.x & 63) == 0) atomicOr(&flag[1], 1);
    if (__any(flt) && (threadIdx.x & 63) == 0) atomicOr(&flag[2], 1);
  }
}

// ---------------- K1: conv1 + flexsig + LN -> y1 (bf16) ----------------
__global__ __launch_bounds__(256, 4)
void k1_mfma(const float* __restrict__ enc, const float* __restrict__ temb,
             const bf16x8* __restrict__ wb1, const float* __restrict__ b1g,
             const float* __restrict__ fa, const float* __restrict__ fb,
             const float* __restrict__ fc, const float* __restrict__ fd,
             const float* __restrict__ g1, const float* __restrict__ be1,
             unsigned short* __restrict__ y1, int b0) {
  __shared__ __attribute__((aligned(16))) char sA[ROWS * CP1B];   // 21760 B
  __shared__ float2 lnbuf[TILE_T][4];
  __shared__ float mu_s[TILE_T], rs_s[TILE_T];

  const int tid = threadIdx.x;
  const int b = b0 + blockIdx.y;
  const int by = blockIdx.y;
  const int t0 = blockIdx.x * TILE_T;
  const int lane = tid & 63;
  const int wid = tid >> 6;
  const int l15 = lane & 15;
  const int lhi = lane >> 4;

  // ---- stage A tile (34 rows x 288 cols, bf16, swizzled) ----
  for (int i = tid; i < ROWS * 36; i += 256) {
    int row = i / 36;
    int g = i - row * 36;
    int t = t0 + row - 1;
    bool tv = (t >= 0) && (t < TT);
    float x[8];
    if (g < 32) {
      if (tv) {
        const float4* p = reinterpret_cast<const float4*>(&enc[((size_t)b * TT + t) * HH + g * 8]);
        float4 v0 = p[0], v1 = p[1];
        x[0] = v0.x; x[1] = v0.y; x[2] = v0.z; x[3] = v0.w;
        x[4] = v1.x; x[5] = v1.y; x[6] = v1.z; x[7] = v1.w;
      } else {
#pragma unroll
        for (int j = 0; j < 8; ++j) x[j] = 0.0f;
      }
    } else if (g < 34) {
      int w0 = (g - 32) * 8;
#pragma unroll
      for (int j = 0; j < 8; ++j) {
        int w = w0 + j;
        float v = 0.0f;
        if (tv) v = (t - w >= 0) ? temb[(size_t)b * TT + t - w] : -1.0f;
        x[j] = v;
      }
    } else {
#pragma unroll
      for (int j = 0; j < 8; ++j) x[j] = 0.0f;
    }
    bf16x8 pk;
#pragma unroll
    for (int j = 0; j < 8; ++j) pk[j] = (short)f2bf(x[j]);
    int byte = row * CP1B + ((g * 16) ^ ((row & 7) << 4));
    *reinterpret_cast<bf16x8*>(&sA[byte]) = pk;
  }
  __syncthreads();

  // ---- MFMA k-loop: wave = M32 x N64 (cols wid*64..wid*64+63) ----
  f32x4 acc[2][4];
#pragma unroll
  for (int mf = 0; mf < 2; ++mf)
#pragma unroll
    for (int nf = 0; nf < 4; ++nf) acc[mf][nf] = (f32x4)(0.0f);

  auto loadA = [&](int ks, bf16x8 aF[2]) {
    int s = (ks >= 2 * NCS1) ? 2 : ((ks >= NCS1) ? 1 : 0);
    int cs = ks - s * NCS1;
    int row0 = l15 + s;
    int cb = (cs * 64 + lhi * 16) ^ ((row0 & 7) << 4);
    int base = row0 * CP1B + cb;
#pragma unroll
    for (int mf = 0; mf < 2; ++mf)
      aF[mf] = *reinterpret_cast<const bf16x8*>(&sA[base + mf * (16 * CP1B)]);
  };
  auto loadB = [&](int ks, bf16x8 bF[4]) {
    const bf16x8* p = wb1 + (size_t)(ks * 16 + wid * 4) * 64 + lane;
#pragma unroll
    for (int nf = 0; nf < 4; ++nf) bF[nf] = p[nf * 64];
  };
  auto mm = [&](bf16x8 aF[2], bf16x8 bF[4]) {
#pragma unroll
    for (int mf = 0; mf < 2; ++mf)
#pragma unroll
      for (int nf = 0; nf < 4; ++nf)
        acc[mf][nf] = __builtin_amdgcn_mfma_f32_16x16x32_bf16(aF[mf], bF[nf], acc[mf][nf], 0, 0, 0);
  };

  bf16x8 aP[2], bP[4], aQ[2], bQ[4];
  loadA(0, aP); loadB(0, bP);
#pragma unroll
  for (int ks = 0; ks + 1 < NK1; ks += 2) {
    loadA(ks + 1, aQ); loadB(ks + 1, bQ);
    mm(aP, bP);
    if (ks + 2 < NK1) { loadA(ks + 2, aP); loadB(ks + 2, bP); }
    mm(aQ, bQ);
  }
  if (NK1 & 1) mm(aP, bP);   // ks = NK1-1 loaded in last iteration

  // ---- flexsig (in-register) ----
  const float fA = fa[0], fB = fb[0], fC = fc[0], fD = fd[0];
  const float inv_c = 1.0f / fC;
#pragma unroll
  for (int mf = 0; mf < 2; ++mf)
#pragma unroll
    for (int nf = 0; nf < 4; ++nf) {
      int col = wid * 64 + nf * 16 + l15;
      float bias = b1g[col];
#pragma unroll
      for (int r = 0; r < 4; ++r)
        acc[mf][nf][r] = flexsig(acc[mf][nf][r] + bias, fA, fB, fC, inv_c, fD);
    }

  // ---- LN stats: per-row partials over this wave's 64 cols ----
#pragma unroll
  for (int mf = 0; mf < 2; ++mf)
#pragma unroll
    for (int r = 0; r < 4; ++r) {
      float s = 0.0f, q = 0.0f;
#pragma unroll
      for (int nf = 0; nf < 4; ++nf) {
        float v = acc[mf][nf][r];
        s += v; q += v * v;
      }
      s += __shfl_xor(s, 1); q += __shfl_xor(q, 1);
      s += __shfl_xor(s, 2); q += __shfl_xor(q, 2);
      s += __shfl_xor(s, 4); q += __shfl_xor(q, 4);
      s += __shfl_xor(s, 8); q += __shfl_xor(q, 8);
      if (l15 == 0) lnbuf[mf * 16 + lhi * 4 + r][wid] = make_float2(s, q);
    }
  __syncthreads();   // also: all waves done reading sA
  if (tid < TILE_T) {
    float S = 0.0f, Q = 0.0f;
#pragma unroll
    for (int w = 0; w < 4; ++w) { S += lnbuf[tid][w].x; Q += lnbuf[tid][w].y; }
    float mu = S * (1.0f / 256.0f);
    float var = Q * (1.0f / 256.0f) - mu * mu;
    mu_s[tid] = mu; rs_s[tid] = rsqrtf(var + 1e-5f);
  }
  __syncthreads();

  // ---- normalize -> bf16 y-tile in LDS (reuse sA), swizzled rows ----
#pragma unroll
  for (int mf = 0; mf < 2; ++mf)
#pragma unroll
    for (int nf = 0; nf < 4; ++nf) {
      int col = wid * 64 + nf * 16 + l15;
      float gg = g1[col], bb = be1[col];
#pragma unroll
      for (int r = 0; r < 4; ++r) {
        int row = mf * 16 + lhi * 4 + r;
        float v = (acc[mf][nf][r] - mu_s[row]) * rs_s[row] * gg + bb;
        int byte = row * 512 + ((col * 2) ^ ((row & 7) << 4));
        *reinterpret_cast<unsigned short*>(&sA[byte]) = f2bf(v);
      }
    }
  __syncthreads();

  // ---- coalesced bf16 store of y1 ----
  for (int i = tid; i < TILE_T * 32; i += 256) {
    int row = i >> 5, g = i & 31;
    int byte = row * 512 + ((g * 16) ^ ((row & 7) << 4));
    bf16x8 v = *reinterpret_cast<const bf16x8*>(&sA[byte]);
    *reinterpret_cast<bf16x8*>(&y1[((size_t)by * TT + t0 + row) * FSZ + g * 8]) = v;
  }
}

// ---------------- K2: conv2 + flexsig + LN + proj + mask -> out ----------------
__global__ __launch_bounds__(256, 4)
void k2_mfma(const unsigned short* __restrict__ y1, const bf16x8* __restrict__ wb2,
             const float* __restrict__ b2g,
             const float* __restrict__ fa, const float* __restrict__ fb,
             const float* __restrict__ fc, const float* __restrict__ fd,
             const float* __restrict__ g2, const float* __restrict__ be2,
             const float* __restrict__ wl, const float* __restrict__ bl,
             const void* __restrict__ maskp, const int* __restrict__ flagp,
             float* __restrict__ out, int b0) {
  __shared__ __attribute__((aligned(16))) char sA[ROWS * CP2B];   // 17408 B
  __shared__ float2 lnbuf[TILE_T][4];
  __shared__ float pbuf[TILE_T][4];
  __shared__ float mu_s[TILE_T], rs_s[TILE_T];

  const int tid = threadIdx.x;
  const int b = b0 + blockIdx.y;
  const int by = blockIdx.y;
  const int t0 = blockIdx.x * TILE_T;
  const int lane = tid & 63;
  const int wid = tid >> 6;
  const int l15 = lane & 15;
  const int lhi = lane >> 4;

  // ---- stage A tile (34 x 256 bf16, swizzled) ----
  for (int i = tid; i < ROWS * 32; i += 256) {
    int row = i >> 5, g = i & 31;
    int t = t0 + row - 1;
    bf16x8 v;
#pragma unroll
    for (int j = 0; j < 8; ++j) v[j] = 0;
    if (t >= 0 && t < TT)
      v = *reinterpret_cast<const bf16x8*>(&y1[((size_t)by * TT + t) * FSZ + g * 8]);
    int byte = row * CP2B + ((g * 16) ^ ((row & 7) << 4));
    *reinterpret_cast<bf16x8*>(&sA[byte]) = v;
  }
  __syncthreads();

  f32x4 acc[2][4];
#pragma unroll
  for (int mf = 0; mf < 2; ++mf)
#pragma unroll
    for (int nf = 0; nf < 4; ++nf) acc[mf][nf] = (f32x4)(0.0f);

  auto loadA = [&](int ks, bf16x8 aF[2]) {
    int s = (ks >= 2 * NCS2) ? 2 : ((ks >= NCS2) ? 1 : 0);
    int cs = ks - s * NCS2;
    int row0 = l15 + s;
    int cb = (cs * 64 + lhi * 16) ^ ((row0 & 7) << 4);
    int base = row0 * CP2B + cb;
#pragma unroll
    for (int mf = 0; mf < 2; ++mf)
      aF[mf] = *reinterpret_cast<const bf16x8*>(&sA[base + mf * (16 * CP2B)]);
  };
  auto loadB = [&](int ks, bf16x8 bF[4]) {
    const bf16x8* p = wb2 + (size_t)(ks * 16 + wid * 4) * 64 + lane;
#pragma unroll
    for (int nf = 0; nf < 4; ++nf) bF[nf] = p[nf * 64];
  };
  auto mm = [&](bf16x8 aF[2], bf16x8 bF[4]) {
#pragma unroll
    for (int mf = 0; mf < 2; ++mf)
#pragma unroll
      for (int nf = 0; nf < 4; ++nf)
        acc[mf][nf] = __builtin_amdgcn_mfma_f32_16x16x32_bf16(aF[mf], bF[nf], acc[mf][nf], 0, 0, 0);
  };

  bf16x8 aP[2], bP[4], aQ[2], bQ[4];
  loadA(0, aP); loadB(0, bP);
#pragma unroll
  for (int ks = 0; ks + 1 < NK2; ks += 2) {
    loadA(ks + 1, aQ); loadB(ks + 1, bQ);
    mm(aP, bP);
    if (ks + 2 < NK2) { loadA(ks + 2, aP); loadB(ks + 2, bP); }
    mm(aQ, bQ);
  }
  if (NK2 & 1) mm(aP, bP);

  const float fA = fa[0], fB = fb[0], fC = fc[0], fD = fd[0];
  const float inv_c = 1.0f / fC;
#pragma unroll
  for (int mf = 0; mf < 2; ++mf)
#pragma unroll
    for (int nf = 0; nf < 4; ++nf) {
      int col = wid * 64 + nf * 16 + l15;
      float bias = b2g[col];
#pragma unroll
      for (int r = 0; r < 4; ++r)
        acc[mf][nf][r] = flexsig(acc[mf][nf][r] + bias, fA, fB, fC, inv_c, fD);
    }

#pragma unroll
  for (int mf = 0; mf < 2; ++mf)
#pragma unroll
    for (int r = 0; r < 4; ++r) {
      float s = 0.0f, q = 0.0f;
#pragma unroll
      for (int nf = 0; nf < 4; ++nf) {
        float v = acc[mf][nf][r];
        s += v; q += v * v;
      }
      s += __shfl_xor(s, 1); q += __shfl_xor(q, 1);
      s += __shfl_xor(s, 2); q += __shfl_xor(q, 2);
      s += __shfl_xor(s, 4); q += __shfl_xor(q, 4);
      s += __shfl_xor(s, 8); q += __shfl_xor(q, 8);
      if (l15 == 0) lnbuf[mf * 16 + lhi * 4 + r][wid] = make_float2(s, q);
    }
  __syncthreads();
  if (tid < TILE_T) {
    float S = 0.0f, Q = 0.0f;
#pragma unroll
    for (int w = 0; w < 4; ++w) { S += lnbuf[tid][w].x; Q += lnbuf[tid][w].y; }
    float mu = S * (1.0f / 256.0f);
    float var = Q * (1.0f / 256.0f) - mu * mu;
    mu_s[tid] = mu; rs_s[tid] = rsqrtf(var + 1e-5f);
  }
  __syncthreads();

  // ---- normalize + projection (in-register), reduce across lanes+waves ----
  float p[2][4];
#pragma unroll
  for (int mf = 0; mf < 2; ++mf)
#pragma unroll
    for (int r = 0; r < 4; ++r) p[mf][r] = 0.0f;
#pragma unroll
  for (int mf = 0; mf < 2; ++mf)
#pragma unroll
    for (int nf = 0; nf < 4; ++nf) {
      int col = wid * 64 + nf * 16 + l15;
      float gg = g2[col], bb = be2[col], ww = wl[col];
#pragma unroll
      for (int r = 0; r < 4; ++r) {
        int row = mf * 16 + lhi * 4 + r;
        float v = (acc[mf][nf][r] - mu_s[row]) * rs_s[row] * gg + bb;
        p[mf][r] += v * ww;
      }
    }
#pragma unroll
  for (int mf = 0; mf < 2; ++mf)
#pragma unroll
    for (int r = 0; r < 4; ++r) {
      float v = p[mf][r];
      v += __shfl_xor(v, 1);
      v += __shfl_xor(v, 2);
      v += __shfl_xor(v, 4);
      v += __shfl_xor(v, 8);
      if (l15 == 0) pbuf[mf * 16 + lhi * 4 + r][wid] = v;
    }
  __syncthreads();
  if (tid < TILE_T) {
    float s = pbuf[tid][0] + pbuf[tid][1] + pbuf[tid][2] + pbuf[tid][3] + bl[0];
    int t = t0 + tid;
    size_t mi = (size_t)b * TT + t;
    int fl = flagp[2] ? 2 : (flagp[1] ? 1 : 0);
    bool m = read_mask(maskp, mi, fl);
    out[mi] = m ? 0.0f : s;
  }
}

// ---------------- host launch ----------------
extern "C" void kernel_launch(void* const* d_in, const int* in_sizes, int n_in,
                              void* d_out, int out_size, void* d_ws, size_t ws_size,
                              hipStream_t stream) {
  const float* enc  = (const float*)d_in[0];
  const void*  maskp= d_in[1];
  const float* temb = (const float*)d_in[2];
  const float* w1   = (const float*)d_in[3];
  const float* b1   = (const float*)d_in[4];
  const float* fa1  = (const float*)d_in[5];
  const float* fb1  = (const float*)d_in[6];
  const float* fc1  = (const float*)d_in[7];
  const float* fd1  = (const float*)d_in[8];
  const float* g1   = (const float*)d_in[9];
  const float* be1  = (const float*)d_in[10];
  const float* w2   = (const float*)d_in[11];
  const float* b2   = (const float*)d_in[12];
  const float* fa2  = (const float*)d_in[13];
  const float* fb2  = (const float*)d_in[14];
  const float* fc2  = (const float*)d_in[15];
  const float* fd2  = (const float*)d_in[16];
  const float* g2   = (const float*)d_in[17];
  const float* be2  = (const float*)d_in[18];
  const float* wl   = (const float*)d_in[19];
  const float* bl   = (const float*)d_in[20];
  float* out = (float*)d_out;

  char* ws = (char*)d_ws;
  const size_t wb1_bytes = (size_t)NK1 * 16 * 64 * 8 * 2;  // 442368
  const size_t wb2_bytes = (size_t)NK2 * 16 * 64 * 8 * 2;  // 393216
  unsigned short* wb1 = (unsigned short*)ws;
  unsigned short* wb2 = (unsigned short*)(ws + wb1_bytes);
  int* flag = (int*)(ws + wb1_bytes + wb2_bytes);
  unsigned short* y1 = (unsigned short*)(ws + wb1_bytes + wb2_bytes + 256);

  const size_t head = wb1_bytes + wb2_bytes + 256;
  const size_t perB = (size_t)TT * FSZ * 2;                // 1 MiB per batch row (bf16)
  size_t avail = (ws_size > head) ? (ws_size - head) : 0;
  size_t cb = avail / perB;
  int chunkB = (cb >= BB) ? BB : (int)cb;
  if (chunkB < 1) chunkB = 1;

  hipMemsetAsync(flag, 0, 16, stream);
  prep_kernel<<<928, 256, 0, stream>>>(w1, w2, wb1, wb2,
                                       (const unsigned int*)maskp, flag);

  for (int b0 = 0; b0 < BB; b0 += chunkB) {
    int nb = (BB - b0 < chunkB) ? (BB - b0) : chunkB;
    dim3 grid(TT / TILE_T, nb);
    k1_mfma<<<grid, 256, 0, stream>>>(enc, temb, (const bf16x8*)wb1, b1,
                                      fa1, fb1, fc1, fd1, g1, be1, y1, b0);
    k2_mfma<<<grid, 256, 0, stream>>>(y1, (const bf16x8*)wb2, b2,
                                      fa2, fb2, fc2, fd2, g2, be2, wl, bl,
                                      maskp, flag, out, b0);
  }
}